// Round 10
// baseline (1185.696 us; speedup 1.0000x reference)
//
#include <hip/hip_runtime.h>
#include <hip/hip_bf16.h>

#define NCH 256      // C
#define NHD 8        // heads
#define HD 32        // head dim
#define NPIX 2304    // 48*48
#define H1DIM 512
#define GSZ 1024u    // persistent grid: 4 blocks/CU x 256 CUs

typedef __attribute__((ext_vector_type(8))) __bf16 bf16x8;
typedef __attribute__((ext_vector_type(4))) float f32x4;

union SMem {
    float tile[64][65];                                  // prep transpose
    struct { float plane[1440]; float wk[49]; } dw;      // dwconv half-plane
    struct { float o[4][32][33]; float l[4][32]; } at;   // attn partials
};

// device-scope grid barrier (G16: device atomics + fences; all blocks resident
// by capacity: 1024 blocks @ __launch_bounds__(256,4) = 4 WGs/CU x 256 CUs)
__device__ __forceinline__ void gridbar(unsigned* cnt, int s) {
    __syncthreads();
    if (threadIdx.x == 0) {
        __threadfence();
        __hip_atomic_fetch_add(&cnt[s], 1u, __ATOMIC_ACQ_REL, __HIP_MEMORY_SCOPE_AGENT);
        while (__hip_atomic_load(&cnt[s], __ATOMIC_ACQUIRE, __HIP_MEMORY_SCOPE_AGENT) < GSZ)
            __builtin_amdgcn_s_sleep(2);
        __threadfence();
    }
    __syncthreads();
}

template <int IC>
__device__ __forceinline__ f32x4 tile16(const __bf16* a, const __bf16* b) {
    f32x4 acc = {0.f, 0.f, 0.f, 0.f};
#pragma unroll
    for (int k = 0; k < IC; k += 32) {
        bf16x8 af = *(const bf16x8*)(a + k);
        bf16x8 bf = *(const bf16x8*)(b + k);
        acc = __builtin_amdgcn_mfma_f32_16x16x32_bf16(af, bf, acc, 0, 0, 0);
    }
    return acc;
}

__global__ __launch_bounds__(256, 4) void mega_k(
    const float* __restrict__ x,
    const float* __restrict__ qk_w, const float* __restrict__ qk_b,
    const float* __restrict__ v_w,  const float* __restrict__ v_b,
    const float* __restrict__ pe_w, const float* __restrict__ pe_b,
    const float* __restrict__ pj_w, const float* __restrict__ pj_b,
    const float* __restrict__ f1_w, const float* __restrict__ f1_b,
    const float* __restrict__ f2_w, const float* __restrict__ f2_b,
    float* __restrict__ out,
    float* __restrict__ v_bu, float* __restrict__ pe_bu, float* __restrict__ x1_f,
    __bf16* __restrict__ Xb, __bf16* __restrict__ opb, __bf16* __restrict__ x1b,
    __bf16* __restrict__ hb, __bf16* __restrict__ Qb, __bf16* __restrict__ Kf,
    __bf16* __restrict__ Vf, __bf16* __restrict__ Wall, unsigned* __restrict__ bar) {

    const int tid = threadIdx.x;
    const int bid = blockIdx.x;
    const int wave = tid >> 6, lane = tid & 63;
    const int l16 = lane & 15, quad = lane >> 4;

    __shared__ SMem sm;

    const __bf16* Wq = Wall;
    const __bf16* Wv = Wall + 131072;
    const __bf16* Wp = Wall + 196608;
    const __bf16* W1 = Wall + 262144;
    const __bf16* W2 = Wall + 393216;

    // ================= stage 0: x NCHW->NHWC bf16 + weight casts =============
    if (bid < 288) {
        const int b = bid / 144, r0 = bid % 144;
        const int c0 = (r0 / 36) * 64, n0 = (r0 % 36) * 64;
        const size_t sb = ((size_t)b * NCH + c0) * NPIX + n0;
#pragma unroll
        for (int i = 0; i < 16; ++i) {
            int idx = tid + i * 256;
            int rr = idx >> 6, cc = idx & 63;
            sm.tile[rr][cc] = x[sb + (size_t)rr * NPIX + cc];
        }
        __syncthreads();
#pragma unroll
        for (int i = 0; i < 8; ++i) {
            int idx = tid + i * 256;
            int nn = idx >> 5, cp = (idx & 31) * 2;
            union { __bf16 h[2]; unsigned u; } pk;
            pk.h[0] = (__bf16)sm.tile[cp][nn];
            pk.h[1] = (__bf16)sm.tile[cp + 1][nn];
            *(unsigned*)&Xb[((size_t)b * NPIX + n0 + nn) * NCH + c0 + cp] = pk.u;
        }
    } else if (bid < 800) {
        int i = (bid - 288) * 256 + tid;   // float4 index over 131072
        const float* src; int off;
        if (i < 32768)      { src = qk_w; off = i; }
        else if (i < 49152) { src = v_w;  off = i - 32768; }
        else if (i < 65536) { src = pj_w; off = i - 49152; }
        else if (i < 98304) { src = f1_w; off = i - 65536; }
        else                { src = f2_w; off = i - 98304; }
        float4 v = ((const float4*)src)[off];
        union { __bf16 h[4]; uint2 u; } pk;
        pk.h[0] = (__bf16)v.x; pk.h[1] = (__bf16)v.y;
        pk.h[2] = (__bf16)v.z; pk.h[3] = (__bf16)v.w;
        ((uint2*)Wall)[i] = pk.u;
    }
    gridbar(bar, 0);

    // ================= stage 1: qk+v conv (13824 wave-tiles) ================
    for (int t = bid * 4 + wave; t < 13824; t += 4096) {
        const int b = t / 6912;
        const int r = t - b * 6912;
        const int yt = r / 144;
        const int px = r - yt * 144;
        const int m0 = px * 16;
        const bool isv = yt >= 32;
        const int oc0 = (isv ? yt - 32 : yt) * 16;

        const __bf16* aptr = Xb + ((size_t)b * NPIX + m0 + l16) * NCH + quad * 8;
        const __bf16* bptr = (isv ? Wv : Wq) + (size_t)(oc0 + l16) * NCH + quad * 8;
        f32x4 acc = tile16<NCH>(aptr, bptr);

        const int oc = oc0 + l16;
        const int mb = m0 + quad * 4;
        if (!isv) {
            const float bb = qk_b[oc];
            const int bh = b * NHD + (oc0 >> 6);
            const int dd = (oc0 & 16) + l16;
            if ((oc0 & 32) == 0) {
                const float qs = 0.17677669529663689f * 1.4426950408889634f;
#pragma unroll
                for (int r2 = 0; r2 < 4; ++r2)
                    Qb[((size_t)bh * NPIX + mb + r2) * 32 + dd] = (__bf16)((acc[r2] + bb) * qs);
            } else {
                __bf16* kp = Kf + ((size_t)(bh * 144 + px) * 64 + (dd >> 3) * 16 + quad * 4) * 8 + (dd & 7);
#pragma unroll
                for (int r2 = 0; r2 < 4; ++r2) kp[r2 * 8] = (__bf16)(acc[r2] + bb);
            }
        } else {
            const float bb = v_b[oc];
            const int bh = b * NHD + (oc0 >> 5);
            const int half = (oc0 >> 4) & 1;
            const size_t fb = ((size_t)b * NCH + oc) * NPIX + mb;
            float4 vf_; float* vp = &vf_.x;
            union { __bf16 hh[4]; uint2 u; } pk;
#pragma unroll
            for (int r2 = 0; r2 < 4; ++r2) {
                float v = acc[r2] + bb;
                vp[r2] = v; pk.hh[r2] = (__bf16)v;
            }
            *(float4*)&v_bu[fb] = vf_;
            *(uint2*)&Vf[((size_t)(bh * 144 + px) * 64 + lane) * 8 + half * 4] = pk.u;
        }
    }
    gridbar(bar, 1);

    // ================= stage 2: depthwise 7x7 (1024 half-plane tasks) =======
    {
        const int c = bid & 255;
        const int b = (bid >> 8) & 1;
        const int half = bid >> 9;
        const int ro = half * 24 - 3;
        const size_t base = ((size_t)b * NCH + c) * NPIX;
        for (int i = tid; i < 1440; i += 256) {
            int rr = ro + i / 48;
            if ((unsigned)rr < 48u) sm.dw.plane[i] = v_bu[base + rr * 48 + (i % 48)];
        }
        if (tid < 49) sm.dw.wk[tid] = pe_w[c * 49 + tid];
        const float bb = pe_b[c];
        __syncthreads();
        for (int p = tid; p < 1152; p += 256) {
            const int py = p / 48, pxx = p - py * 48;
            const int y = half * 24 + py;
            float s = bb;
#pragma unroll
            for (int ky = 0; ky < 7; ++ky) {
                const int yy = y + ky - 3;
                if ((unsigned)yy < 48u) {
#pragma unroll
                    for (int kx = 0; kx < 7; ++kx) {
                        const int xx = pxx + kx - 3;
                        if ((unsigned)xx < 48u)
                            s += sm.dw.wk[ky * 7 + kx] * sm.dw.plane[(py + ky) * 48 + xx];
                    }
                }
            }
            pe_bu[base + y * 48 + pxx] = s;
        }
    }
    gridbar(bar, 2);

    // ================= stage 3: attention (1152 tasks, in-WG kv-split 4) ====
    for (int task = bid; task < 1152; task += 1024) {
        const int qt = task % 72;
        const int hb_ = task / 72;
        const int h = hb_ & 7, b = hb_ >> 3;
        const int bh = b * NHD + h;
        const int qb_ = qt * 32;

        bf16x8 b_q0 = *(const bf16x8*)(Qb + ((size_t)bh * NPIX + qb_ + l16) * 32 + quad * 8);
        bf16x8 b_q1 = *(const bf16x8*)(Qb + ((size_t)bh * NPIX + qb_ + 16 + l16) * 32 + quad * 8);
        const __bf16* kf = Kf + ((size_t)(bh * 144 + wave * 36) * 64 + lane) * 8;
        const __bf16* vf = Vf + ((size_t)(bh * 144 + wave * 36) * 64 + lane) * 8;

        f32x4 o00 = {0.f,0.f,0.f,0.f}, o01 = {0.f,0.f,0.f,0.f};
        f32x4 o10 = {0.f,0.f,0.f,0.f}, o11 = {0.f,0.f,0.f,0.f};
        f32x4 l0 = {0.f,0.f,0.f,0.f}, l1 = {0.f,0.f,0.f,0.f};

#pragma unroll 4
        for (int t = 0; t < 36; ++t) {
            bf16x8 a_k = *(const bf16x8*)(kf + (size_t)t * 512);
            bf16x8 va  = *(const bf16x8*)(vf + (size_t)t * 512);
            f32x4 z = {0.f, 0.f, 0.f, 0.f};
            f32x4 s0 = __builtin_amdgcn_mfma_f32_16x16x32_bf16(a_k, b_q0, z, 0, 0, 0);
            f32x4 s1 = __builtin_amdgcn_mfma_f32_16x16x32_bf16(a_k, b_q1, z, 0, 0, 0);
            f32x4 p0, p1;
#pragma unroll
            for (int r = 0; r < 4; ++r) {
                p0[r] = __builtin_amdgcn_exp2f(s0[r]);
                p1[r] = __builtin_amdgcn_exp2f(s1[r]);
            }
            l0 += p0; l1 += p1;
            bf16x8 b0lo = {}, b0hi = {}, b1lo = {}, b1hi = {};
#pragma unroll
            for (int r = 0; r < 4; ++r) {
                __bf16 c0 = (__bf16)p0[r], c1 = (__bf16)p1[r];
                b0lo[r] = c0; b0hi[4 + r] = c0;
                b1lo[r] = c1; b1hi[4 + r] = c1;
            }
            o00 = __builtin_amdgcn_mfma_f32_16x16x32_bf16(va, b0lo, o00, 0, 0, 0);
            o01 = __builtin_amdgcn_mfma_f32_16x16x32_bf16(va, b0hi, o01, 0, 0, 0);
            o10 = __builtin_amdgcn_mfma_f32_16x16x32_bf16(va, b1lo, o10, 0, 0, 0);
            o11 = __builtin_amdgcn_mfma_f32_16x16x32_bf16(va, b1hi, o11, 0, 0, 0);
        }

        float ls0 = l0[0] + l0[1] + l0[2] + l0[3];
        ls0 += __shfl_xor(ls0, 16); ls0 += __shfl_xor(ls0, 32);
        float ls1 = l1[0] + l1[1] + l1[2] + l1[3];
        ls1 += __shfl_xor(ls1, 16); ls1 += __shfl_xor(ls1, 32);

#pragma unroll
        for (int r = 0; r < 4; ++r) {
            sm.at.o[wave][quad * 4 + r][l16]           = o00[r];
            sm.at.o[wave][16 + quad * 4 + r][l16]      = o01[r];
            sm.at.o[wave][quad * 4 + r][16 + l16]      = o10[r];
            sm.at.o[wave][16 + quad * 4 + r][16 + l16] = o11[r];
        }
        if (quad == 0) { sm.at.l[wave][l16] = ls0; sm.at.l[wave][16 + l16] = ls1; }
        __syncthreads();

        const int q = tid & 31;
        const int d0 = (tid >> 5) * 4;
        float l = sm.at.l[0][q] + sm.at.l[1][q] + sm.at.l[2][q] + sm.at.l[3][q];
        const float inv = 1.f / l;
        const int n = qb_ + q;
        union { __bf16 hh[4]; uint2 u; } pk;
#pragma unroll
        for (int j = 0; j < 4; ++j) {
            float v = sm.at.o[0][d0 + j][q] + sm.at.o[1][d0 + j][q] +
                      sm.at.o[2][d0 + j][q] + sm.at.o[3][d0 + j][q];
            v = v * inv + pe_bu[((size_t)b * NCH + h * HD + d0 + j) * NPIX + n];
            pk.hh[j] = (__bf16)v;
        }
        *(uint2*)&opb[((size_t)b * NPIX + n) * NCH + h * HD + d0] = pk.u;
        __syncthreads();
    }
    gridbar(bar, 3);

    // ================= stage 4: proj + x resid (4608 wave-tiles) ============
    for (int t = bid * 4 + wave; t < 4608; t += 4096) {
        const int b = t / 2304;
        const int r = t - b * 2304;
        const int oc0 = (r / 144) * 16;
        const int m0 = (r % 144) * 16;
        const __bf16* aptr = opb + ((size_t)b * NPIX + m0 + l16) * NCH + quad * 8;
        const __bf16* bptr = Wp + (size_t)(oc0 + l16) * NCH + quad * 8;
        f32x4 acc = tile16<NCH>(aptr, bptr);
        const int oc = oc0 + l16, mb = m0 + quad * 4;
        const float bb = pj_b[oc];
        const size_t fb = ((size_t)b * NCH + oc) * NPIX + mb;
        float4 xr = *(const float4*)&x[fb];
        const float* xp = &xr.x;
        float4 vf_; float* vp = &vf_.x;
#pragma unroll
        for (int r2 = 0; r2 < 4; ++r2) {
            float v = acc[r2] + bb + xp[r2];
            vp[r2] = v;
            x1b[((size_t)b * NPIX + mb + r2) * NCH + oc] = (__bf16)v;
        }
        *(float4*)&x1_f[fb] = vf_;
    }
    gridbar(bar, 4);

    // ================= stage 5: fc1 + silu (9216 wave-tiles) ================
    for (int t = bid * 4 + wave; t < 9216; t += 4096) {
        const int b = t / 4608;
        const int r = t - b * 4608;
        const int oc0 = (r / 144) * 16;
        const int m0 = (r % 144) * 16;
        const __bf16* aptr = x1b + ((size_t)b * NPIX + m0 + l16) * NCH + quad * 8;
        const __bf16* bptr = W1 + (size_t)(oc0 + l16) * NCH + quad * 8;
        f32x4 acc = tile16<NCH>(aptr, bptr);
        const int oc = oc0 + l16, mb = m0 + quad * 4;
        const float bb = f1_b[oc];
#pragma unroll
        for (int r2 = 0; r2 < 4; ++r2) {
            float v = acc[r2] + bb;
            v = v / (1.f + __expf(-v));
            hb[((size_t)b * NPIX + mb + r2) * H1DIM + oc] = (__bf16)v;
        }
    }
    gridbar(bar, 5);

    // ================= stage 6: fc2 + x1 resid -> out (4608 wave-tiles) =====
    for (int t = bid * 4 + wave; t < 4608; t += 4096) {
        const int b = t / 2304;
        const int r = t - b * 2304;
        const int oc0 = (r / 144) * 16;
        const int m0 = (r % 144) * 16;
        const __bf16* aptr = hb + ((size_t)b * NPIX + m0 + l16) * H1DIM + quad * 8;
        const __bf16* bptr = W2 + (size_t)(oc0 + l16) * H1DIM + quad * 8;
        f32x4 acc = tile16<H1DIM>(aptr, bptr);
        const int oc = oc0 + l16, mb = m0 + quad * 4;
        const float bb = f2_b[oc];
        const size_t fb = ((size_t)b * NCH + oc) * NPIX + mb;
        float4 xr = *(const float4*)&x1_f[fb];
        const float* xp = &xr.x;
        float4 vf_; float* vp = &vf_.x;
#pragma unroll
        for (int r2 = 0; r2 < 4; ++r2) vp[r2] = acc[r2] + bb + xp[r2];
        *(float4*)&out[fb] = vf_;
    }
}

extern "C" void kernel_launch(void* const* d_in, const int* in_sizes, int n_in,
                              void* d_out, int out_size, void* d_ws, size_t ws_size,
                              hipStream_t stream) {
    const float* x    = (const float*)d_in[0];
    const float* qk_w = (const float*)d_in[1];
    const float* qk_b = (const float*)d_in[2];
    const float* v_w  = (const float*)d_in[3];
    const float* v_b  = (const float*)d_in[4];
    const float* pe_w = (const float*)d_in[5];
    const float* pe_b = (const float*)d_in[6];
    const float* pj_w = (const float*)d_in[7];
    const float* pj_b = (const float*)d_in[8];
    const float* f1_w = (const float*)d_in[9];
    const float* f1_b = (const float*)d_in[10];
    const float* f2_w = (const float*)d_in[11];
    const float* f2_b = (const float*)d_in[12];
    float* out = (float*)d_out;

    const int B = 2;
    const size_t plane = (size_t)NCH * NPIX;       // 589824
    const size_t bp = (size_t)B * plane;           // 1179648

    float* v_bu  = (float*)d_ws;                   // NCHW f32
    float* pe_bu = v_bu + bp;
    float* x1_f  = pe_bu + bp;
    __bf16* Xb   = (__bf16*)(x1_f + bp);           // NHWC bf16 [b][n][256]
    __bf16* opb  = Xb + bp;                        // NHWC bf16 (attn+pe)
    __bf16* x1b  = opb + bp;                       // NHWC bf16
    __bf16* hb   = x1b + bp;                       // NHWC bf16 [b][n][512]
    __bf16* Qb   = hb + 2 * bp;                    // [bh][n][32] (pre-scaled)
    __bf16* Kf   = Qb + bp;                        // QK A-frag tiles
    __bf16* Vf   = Kf + bp;                        // PV A-frag tiles
    __bf16* Wall = Vf + bp;                        // 524288 bf16
    unsigned* bar = (unsigned*)(Wall + 524288);    // 8 barrier slots

    hipMemsetAsync(bar, 0, 64, stream);
    mega_k<<<GSZ, 256, 0, stream>>>(
        x, qk_w, qk_b, v_w, v_b, pe_w, pe_b, pj_w, pj_b,
        f1_w, f1_b, f2_w, f2_b, out,
        v_bu, pe_bu, x1_f, Xb, opb, x1b, hb, Qb, Kf, Vf, Wall, bar);
}

// Round 11
// 956.923 us; speedup vs baseline: 1.2391x; 1.2391x over previous
//
#include <hip/hip_runtime.h>
#include <hip/hip_bf16.h>

#define NCH 256      // C
#define NHD 8        // heads
#define HD 32        // head dim
#define NPIX 2304    // 48*48
#define H1DIM 512
#define GSZ 1024u    // persistent grid: 4 blocks/CU x 256 CUs

typedef __attribute__((ext_vector_type(8))) __bf16 bf16x8;
typedef __attribute__((ext_vector_type(4))) float f32x4;

union SMem {
    float tile[64][65];                                  // prep transpose
    struct { float plane[1440]; float wk[49]; } dw;      // dwconv half-plane
    struct { float o[4][32][33]; float l[4][32]; } at;   // attn partials
};

// device-scope grid barrier. R10 post-mortem: per-poll ACQUIRE emitted a cache
// invalidate every iteration (1024 spinners -> chip-wide L2-invalidate storm,
// ~190us/barrier). Fix: RELEASE add + RELAXED polls (scope alone makes the
// poll visible at the coherence point, no invalidates) + ONE acquire fence
// after exit.
__device__ __forceinline__ void gridbar(unsigned* cnt, int s) {
    __syncthreads();
    if (threadIdx.x == 0) {
        __threadfence();   // release: write back my dirty lines once
        __hip_atomic_fetch_add(&cnt[s], 1u, __ATOMIC_RELEASE, __HIP_MEMORY_SCOPE_AGENT);
        while (__hip_atomic_load(&cnt[s], __ATOMIC_RELAXED, __HIP_MEMORY_SCOPE_AGENT) < GSZ)
            __builtin_amdgcn_s_sleep(8);
        __threadfence();   // acquire: invalidate stale lines once
    }
    __syncthreads();
}

template <int IC>
__device__ __forceinline__ f32x4 tile16(const __bf16* a, const __bf16* b) {
    f32x4 acc = {0.f, 0.f, 0.f, 0.f};
#pragma unroll
    for (int k = 0; k < IC; k += 32) {
        bf16x8 af = *(const bf16x8*)(a + k);
        bf16x8 bf = *(const bf16x8*)(b + k);
        acc = __builtin_amdgcn_mfma_f32_16x16x32_bf16(af, bf, acc, 0, 0, 0);
    }
    return acc;
}

__global__ __launch_bounds__(256, 4) void mega_k(
    const float* __restrict__ x,
    const float* __restrict__ qk_w, const float* __restrict__ qk_b,
    const float* __restrict__ v_w,  const float* __restrict__ v_b,
    const float* __restrict__ pe_w, const float* __restrict__ pe_b,
    const float* __restrict__ pj_w, const float* __restrict__ pj_b,
    const float* __restrict__ f1_w, const float* __restrict__ f1_b,
    const float* __restrict__ f2_w, const float* __restrict__ f2_b,
    float* __restrict__ out,
    float* __restrict__ v_bu, float* __restrict__ pe_bu, float* __restrict__ x1_f,
    __bf16* __restrict__ Xb, __bf16* __restrict__ opb, __bf16* __restrict__ x1b,
    __bf16* __restrict__ hb, __bf16* __restrict__ Qb, __bf16* __restrict__ Kf,
    __bf16* __restrict__ Vf, __bf16* __restrict__ Wall, unsigned* __restrict__ bar) {

    const int tid = threadIdx.x;
    const int bid = blockIdx.x;
    const int wave = tid >> 6, lane = tid & 63;
    const int l16 = lane & 15, quad = lane >> 4;

    __shared__ SMem sm;

    const __bf16* Wq = Wall;
    const __bf16* Wv = Wall + 131072;
    const __bf16* Wp = Wall + 196608;
    const __bf16* W1 = Wall + 262144;
    const __bf16* W2 = Wall + 393216;

    // ================= stage 0: x NCHW->NHWC bf16 + weight casts =============
    if (bid < 288) {
        const int b = bid / 144, r0 = bid % 144;
        const int c0 = (r0 / 36) * 64, n0 = (r0 % 36) * 64;
        const size_t sb = ((size_t)b * NCH + c0) * NPIX + n0;
#pragma unroll
        for (int i = 0; i < 16; ++i) {
            int idx = tid + i * 256;
            int rr = idx >> 6, cc = idx & 63;
            sm.tile[rr][cc] = x[sb + (size_t)rr * NPIX + cc];
        }
        __syncthreads();
#pragma unroll
        for (int i = 0; i < 8; ++i) {
            int idx = tid + i * 256;
            int nn = idx >> 5, cp = (idx & 31) * 2;
            union { __bf16 h[2]; unsigned u; } pk;
            pk.h[0] = (__bf16)sm.tile[cp][nn];
            pk.h[1] = (__bf16)sm.tile[cp + 1][nn];
            *(unsigned*)&Xb[((size_t)b * NPIX + n0 + nn) * NCH + c0 + cp] = pk.u;
        }
    } else if (bid < 800) {
        int i = (bid - 288) * 256 + tid;   // float4 index over 131072
        const float* src; int off;
        if (i < 32768)      { src = qk_w; off = i; }
        else if (i < 49152) { src = v_w;  off = i - 32768; }
        else if (i < 65536) { src = pj_w; off = i - 49152; }
        else if (i < 98304) { src = f1_w; off = i - 65536; }
        else                { src = f2_w; off = i - 98304; }
        float4 v = ((const float4*)src)[off];
        union { __bf16 h[4]; uint2 u; } pk;
        pk.h[0] = (__bf16)v.x; pk.h[1] = (__bf16)v.y;
        pk.h[2] = (__bf16)v.z; pk.h[3] = (__bf16)v.w;
        ((uint2*)Wall)[i] = pk.u;
    }
    gridbar(bar, 0);

    // ================= stage 1: qk+v conv (13824 wave-tiles) ================
    for (int t = bid * 4 + wave; t < 13824; t += 4096) {
        const int b = t / 6912;
        const int r = t - b * 6912;
        const int yt = r / 144;
        const int px = r - yt * 144;
        const int m0 = px * 16;
        const bool isv = yt >= 32;
        const int oc0 = (isv ? yt - 32 : yt) * 16;

        const __bf16* aptr = Xb + ((size_t)b * NPIX + m0 + l16) * NCH + quad * 8;
        const __bf16* bptr = (isv ? Wv : Wq) + (size_t)(oc0 + l16) * NCH + quad * 8;
        f32x4 acc = tile16<NCH>(aptr, bptr);

        const int oc = oc0 + l16;
        const int mb = m0 + quad * 4;
        if (!isv) {
            const float bb = qk_b[oc];
            const int bh = b * NHD + (oc0 >> 6);
            const int dd = (oc0 & 16) + l16;
            if ((oc0 & 32) == 0) {
                const float qs = 0.17677669529663689f * 1.4426950408889634f;
#pragma unroll
                for (int r2 = 0; r2 < 4; ++r2)
                    Qb[((size_t)bh * NPIX + mb + r2) * 32 + dd] = (__bf16)((acc[r2] + bb) * qs);
            } else {
                __bf16* kp = Kf + ((size_t)(bh * 144 + px) * 64 + (dd >> 3) * 16 + quad * 4) * 8 + (dd & 7);
#pragma unroll
                for (int r2 = 0; r2 < 4; ++r2) kp[r2 * 8] = (__bf16)(acc[r2] + bb);
            }
        } else {
            const float bb = v_b[oc];
            const int bh = b * NHD + (oc0 >> 5);
            const int half = (oc0 >> 4) & 1;
            const size_t fb = ((size_t)b * NCH + oc) * NPIX + mb;
            float4 vf_; float* vp = &vf_.x;
            union { __bf16 hh[4]; uint2 u; } pk;
#pragma unroll
            for (int r2 = 0; r2 < 4; ++r2) {
                float v = acc[r2] + bb;
                vp[r2] = v; pk.hh[r2] = (__bf16)v;
            }
            *(float4*)&v_bu[fb] = vf_;
            *(uint2*)&Vf[((size_t)(bh * 144 + px) * 64 + lane) * 8 + half * 4] = pk.u;
        }
    }
    gridbar(bar, 1);

    // ================= stage 2: depthwise 7x7 (1024 half-plane tasks) =======
    {
        const int c = bid & 255;
        const int b = (bid >> 8) & 1;
        const int half = bid >> 9;
        const int ro = half * 24 - 3;
        const size_t base = ((size_t)b * NCH + c) * NPIX;
        for (int i = tid; i < 1440; i += 256) {
            int rr = ro + i / 48;
            if ((unsigned)rr < 48u) sm.dw.plane[i] = v_bu[base + rr * 48 + (i % 48)];
        }
        if (tid < 49) sm.dw.wk[tid] = pe_w[c * 49 + tid];
        const float bb = pe_b[c];
        __syncthreads();
        for (int p = tid; p < 1152; p += 256) {
            const int py = p / 48, pxx = p - py * 48;
            const int y = half * 24 + py;
            float s = bb;
#pragma unroll
            for (int ky = 0; ky < 7; ++ky) {
                const int yy = y + ky - 3;
                if ((unsigned)yy < 48u) {
#pragma unroll
                    for (int kx = 0; kx < 7; ++kx) {
                        const int xx = pxx + kx - 3;
                        if ((unsigned)xx < 48u)
                            s += sm.dw.wk[ky * 7 + kx] * sm.dw.plane[(py + ky) * 48 + xx];
                    }
                }
            }
            pe_bu[base + y * 48 + pxx] = s;
        }
    }
    gridbar(bar, 2);

    // ================= stage 3: attention (1152 tasks, in-WG kv-split 4) ====
    for (int task = bid; task < 1152; task += 1024) {
        const int qt = task % 72;
        const int hb_ = task / 72;
        const int h = hb_ & 7, b = hb_ >> 3;
        const int bh = b * NHD + h;
        const int qb_ = qt * 32;

        bf16x8 b_q0 = *(const bf16x8*)(Qb + ((size_t)bh * NPIX + qb_ + l16) * 32 + quad * 8);
        bf16x8 b_q1 = *(const bf16x8*)(Qb + ((size_t)bh * NPIX + qb_ + 16 + l16) * 32 + quad * 8);
        const __bf16* kf = Kf + ((size_t)(bh * 144 + wave * 36) * 64 + lane) * 8;
        const __bf16* vf = Vf + ((size_t)(bh * 144 + wave * 36) * 64 + lane) * 8;

        f32x4 o00 = {0.f,0.f,0.f,0.f}, o01 = {0.f,0.f,0.f,0.f};
        f32x4 o10 = {0.f,0.f,0.f,0.f}, o11 = {0.f,0.f,0.f,0.f};
        f32x4 l0 = {0.f,0.f,0.f,0.f}, l1 = {0.f,0.f,0.f,0.f};

#pragma unroll 4
        for (int t = 0; t < 36; ++t) {
            bf16x8 a_k = *(const bf16x8*)(kf + (size_t)t * 512);
            bf16x8 va  = *(const bf16x8*)(vf + (size_t)t * 512);
            f32x4 z = {0.f, 0.f, 0.f, 0.f};
            f32x4 s0 = __builtin_amdgcn_mfma_f32_16x16x32_bf16(a_k, b_q0, z, 0, 0, 0);
            f32x4 s1 = __builtin_amdgcn_mfma_f32_16x16x32_bf16(a_k, b_q1, z, 0, 0, 0);
            f32x4 p0, p1;
#pragma unroll
            for (int r = 0; r < 4; ++r) {
                p0[r] = __builtin_amdgcn_exp2f(s0[r]);
                p1[r] = __builtin_amdgcn_exp2f(s1[r]);
            }
            l0 += p0; l1 += p1;
            bf16x8 b0lo = {}, b0hi = {}, b1lo = {}, b1hi = {};
#pragma unroll
            for (int r = 0; r < 4; ++r) {
                __bf16 c0 = (__bf16)p0[r], c1 = (__bf16)p1[r];
                b0lo[r] = c0; b0hi[4 + r] = c0;
                b1lo[r] = c1; b1hi[4 + r] = c1;
            }
            o00 = __builtin_amdgcn_mfma_f32_16x16x32_bf16(va, b0lo, o00, 0, 0, 0);
            o01 = __builtin_amdgcn_mfma_f32_16x16x32_bf16(va, b0hi, o01, 0, 0, 0);
            o10 = __builtin_amdgcn_mfma_f32_16x16x32_bf16(va, b1lo, o10, 0, 0, 0);
            o11 = __builtin_amdgcn_mfma_f32_16x16x32_bf16(va, b1hi, o11, 0, 0, 0);
        }

        float ls0 = l0[0] + l0[1] + l0[2] + l0[3];
        ls0 += __shfl_xor(ls0, 16); ls0 += __shfl_xor(ls0, 32);
        float ls1 = l1[0] + l1[1] + l1[2] + l1[3];
        ls1 += __shfl_xor(ls1, 16); ls1 += __shfl_xor(ls1, 32);

#pragma unroll
        for (int r = 0; r < 4; ++r) {
            sm.at.o[wave][quad * 4 + r][l16]           = o00[r];
            sm.at.o[wave][16 + quad * 4 + r][l16]      = o01[r];
            sm.at.o[wave][quad * 4 + r][16 + l16]      = o10[r];
            sm.at.o[wave][16 + quad * 4 + r][16 + l16] = o11[r];
        }
        if (quad == 0) { sm.at.l[wave][l16] = ls0; sm.at.l[wave][16 + l16] = ls1; }
        __syncthreads();

        const int q = tid & 31;
        const int d0 = (tid >> 5) * 4;
        float l = sm.at.l[0][q] + sm.at.l[1][q] + sm.at.l[2][q] + sm.at.l[3][q];
        const float inv = 1.f / l;
        const int n = qb_ + q;
        union { __bf16 hh[4]; uint2 u; } pk;
#pragma unroll
        for (int j = 0; j < 4; ++j) {
            float v = sm.at.o[0][d0 + j][q] + sm.at.o[1][d0 + j][q] +
                      sm.at.o[2][d0 + j][q] + sm.at.o[3][d0 + j][q];
            v = v * inv + pe_bu[((size_t)b * NCH + h * HD + d0 + j) * NPIX + n];
            pk.hh[j] = (__bf16)v;
        }
        *(uint2*)&opb[((size_t)b * NPIX + n) * NCH + h * HD + d0] = pk.u;
        __syncthreads();
    }
    gridbar(bar, 3);

    // ================= stage 4: proj + x resid (4608 wave-tiles) ============
    for (int t = bid * 4 + wave; t < 4608; t += 4096) {
        const int b = t / 2304;
        const int r = t - b * 2304;
        const int oc0 = (r / 144) * 16;
        const int m0 = (r % 144) * 16;
        const __bf16* aptr = opb + ((size_t)b * NPIX + m0 + l16) * NCH + quad * 8;
        const __bf16* bptr = Wp + (size_t)(oc0 + l16) * NCH + quad * 8;
        f32x4 acc = tile16<NCH>(aptr, bptr);
        const int oc = oc0 + l16, mb = m0 + quad * 4;
        const float bb = pj_b[oc];
        const size_t fb = ((size_t)b * NCH + oc) * NPIX + mb;
        float4 xr = *(const float4*)&x[fb];
        const float* xp = &xr.x;
        float4 vf_; float* vp = &vf_.x;
#pragma unroll
        for (int r2 = 0; r2 < 4; ++r2) {
            float v = acc[r2] + bb + xp[r2];
            vp[r2] = v;
            x1b[((size_t)b * NPIX + mb + r2) * NCH + oc] = (__bf16)v;
        }
        *(float4*)&x1_f[fb] = vf_;
    }
    gridbar(bar, 4);

    // ================= stage 5: fc1 + silu (9216 wave-tiles) ================
    for (int t = bid * 4 + wave; t < 9216; t += 4096) {
        const int b = t / 4608;
        const int r = t - b * 4608;
        const int oc0 = (r / 144) * 16;
        const int m0 = (r % 144) * 16;
        const __bf16* aptr = x1b + ((size_t)b * NPIX + m0 + l16) * NCH + quad * 8;
        const __bf16* bptr = W1 + (size_t)(oc0 + l16) * NCH + quad * 8;
        f32x4 acc = tile16<NCH>(aptr, bptr);
        const int oc = oc0 + l16, mb = m0 + quad * 4;
        const float bb = f1_b[oc];
#pragma unroll
        for (int r2 = 0; r2 < 4; ++r2) {
            float v = acc[r2] + bb;
            v = v / (1.f + __expf(-v));
            hb[((size_t)b * NPIX + mb + r2) * H1DIM + oc] = (__bf16)v;
        }
    }
    gridbar(bar, 5);

    // ================= stage 6: fc2 + x1 resid -> out (4608 wave-tiles) =====
    for (int t = bid * 4 + wave; t < 4608; t += 4096) {
        const int b = t / 2304;
        const int r = t - b * 2304;
        const int oc0 = (r / 144) * 16;
        const int m0 = (r % 144) * 16;
        const __bf16* aptr = hb + ((size_t)b * NPIX + m0 + l16) * H1DIM + quad * 8;
        const __bf16* bptr = W2 + (size_t)(oc0 + l16) * H1DIM + quad * 8;
        f32x4 acc = tile16<H1DIM>(aptr, bptr);
        const int oc = oc0 + l16, mb = m0 + quad * 4;
        const float bb = f2_b[oc];
        const size_t fb = ((size_t)b * NCH + oc) * NPIX + mb;
        float4 xr = *(const float4*)&x1_f[fb];
        const float* xp = &xr.x;
        float4 vf_; float* vp = &vf_.x;
#pragma unroll
        for (int r2 = 0; r2 < 4; ++r2) vp[r2] = acc[r2] + bb + xp[r2];
        *(float4*)&out[fb] = vf_;
    }
}

extern "C" void kernel_launch(void* const* d_in, const int* in_sizes, int n_in,
                              void* d_out, int out_size, void* d_ws, size_t ws_size,
                              hipStream_t stream) {
    const float* x    = (const float*)d_in[0];
    const float* qk_w = (const float*)d_in[1];
    const float* qk_b = (const float*)d_in[2];
    const float* v_w  = (const float*)d_in[3];
    const float* v_b  = (const float*)d_in[4];
    const float* pe_w = (const float*)d_in[5];
    const float* pe_b = (const float*)d_in[6];
    const float* pj_w = (const float*)d_in[7];
    const float* pj_b = (const float*)d_in[8];
    const float* f1_w = (const float*)d_in[9];
    const float* f1_b = (const float*)d_in[10];
    const float* f2_w = (const float*)d_in[11];
    const float* f2_b = (const float*)d_in[12];
    float* out = (float*)d_out;

    const int B = 2;
    const size_t plane = (size_t)NCH * NPIX;       // 589824
    const size_t bp = (size_t)B * plane;           // 1179648

    float* v_bu  = (float*)d_ws;                   // NCHW f32
    float* pe_bu = v_bu + bp;
    float* x1_f  = pe_bu + bp;
    __bf16* Xb   = (__bf16*)(x1_f + bp);           // NHWC bf16 [b][n][256]
    __bf16* opb  = Xb + bp;                        // NHWC bf16 (attn+pe)
    __bf16* x1b  = opb + bp;                       // NHWC bf16
    __bf16* hb   = x1b + bp;                       // NHWC bf16 [b][n][512]
    __bf16* Qb   = hb + 2 * bp;                    // [bh][n][32] (pre-scaled)
    __bf16* Kf   = Qb + bp;                        // QK A-frag tiles
    __bf16* Vf   = Kf + bp;                        // PV A-frag tiles
    __bf16* Wall = Vf + bp;                        // 524288 bf16
    unsigned* bar = (unsigned*)(Wall + 524288);    // 8 barrier slots

    hipMemsetAsync(bar, 0, 64, stream);
    mega_k<<<GSZ, 256, 0, stream>>>(
        x, qk_w, qk_b, v_w, v_b, pe_w, pe_b, pj_w, pj_b,
        f1_w, f1_b, f2_w, f2_b, out,
        v_bu, pe_bu, x1_f, Xb, opb, x1b, hb, Qb, Kf, Vf, Wall, bar);
}

// Round 12
// 209.320 us; speedup vs baseline: 5.6645x; 4.5716x over previous
//
#include <hip/hip_runtime.h>
#include <hip/hip_bf16.h>

#define NCH 256      // C
#define NHD 8        // heads
#define HD 32        // head dim
#define NPIX 2304    // 48*48
#define H1DIM 512

typedef __attribute__((ext_vector_type(8))) __bf16 bf16x8;
typedef __attribute__((ext_vector_type(4))) float f32x4;

// ---------------- prep: x NCHW f32 -> NHWC bf16  +  weight cast --------------
// blocks [0,288): transpose;  blocks [288,800): weight cast (5 matrices)
__global__ __launch_bounds__(256) void prep_k(
    const float* __restrict__ x,
    const float* __restrict__ w0, const float* __restrict__ w1,
    const float* __restrict__ w2, const float* __restrict__ w3,
    const float* __restrict__ w4,
    __bf16* __restrict__ Xb, __bf16* __restrict__ Wall) {
    const int tid = threadIdx.x;
    if (blockIdx.x < 288) {
        const int t = blockIdx.x;
        const int b = t / 144, r0 = t % 144;
        const int c0 = (r0 / 36) * 64, n0 = (r0 % 36) * 64;
        __shared__ float tile[64][65];
        const size_t sb = ((size_t)b * NCH + c0) * NPIX + n0;
#pragma unroll
        for (int i = 0; i < 16; ++i) {
            int idx = tid + i * 256;
            int rr = idx >> 6, cc = idx & 63;
            tile[rr][cc] = x[sb + (size_t)rr * NPIX + cc];
        }
        __syncthreads();
#pragma unroll
        for (int i = 0; i < 8; ++i) {
            int idx = tid + i * 256;
            int nn = idx >> 5, cp = (idx & 31) * 2;
            union { __bf16 h[2]; unsigned u; } pk;
            pk.h[0] = (__bf16)tile[cp][nn];
            pk.h[1] = (__bf16)tile[cp + 1][nn];
            *(unsigned*)&Xb[((size_t)b * NPIX + n0 + nn) * NCH + c0 + cp] = pk.u;
        }
    } else {
        int i = (blockIdx.x - 288) * 256 + tid;   // float4 index over 131072
        const float* src; int off;
        if (i < 32768)      { src = w0; off = i; }
        else if (i < 49152) { src = w1; off = i - 32768; }
        else if (i < 65536) { src = w2; off = i - 49152; }
        else if (i < 98304) { src = w3; off = i - 65536; }
        else                { src = w4; off = i - 98304; }
        float4 v = ((const float4*)src)[off];
        union { __bf16 h[4]; uint2 u; } pk;
        pk.h[0] = (__bf16)v.x; pk.h[1] = (__bf16)v.y;
        pk.h[2] = (__bf16)v.z; pk.h[3] = (__bf16)v.w;
        ((uint2*)Wall)[i] = pk.u;
    }
}

// ---------------- fused qk+v conv, head-pinned to XCD (bid&7 = head) ---------
// 1D grid 3456 blocks x 4 waves; per-head task tau in [0,1728):
// px = tau%144; b = (tau/144)&1; sub = tau/288: 0-3 qk (oc0=64h+16sub),
// 4-5 v (oc0=32h+16(sub-4)).
__global__ __launch_bounds__(256) void qkv_k(
    const __bf16* __restrict__ A, const __bf16* __restrict__ Wq,
    const __bf16* __restrict__ Wv, const float* __restrict__ qk_b,
    const float* __restrict__ v_b, __bf16* __restrict__ Qb,
    __bf16* __restrict__ Kf, float* __restrict__ v_bu,
    __bf16* __restrict__ Vf) {
    const int tid = threadIdx.x;
    const int wave = tid >> 6, lane = tid & 63;
    const int l16 = lane & 15, quad = lane >> 4;
    const int h = blockIdx.x & 7;
    const int u = blockIdx.x >> 3;        // [0,432)
    const int tau = u * 4 + wave;         // [0,1728); 144%4==0 -> no straddle
    const int px = tau % 144;
    const int rest = tau / 144;           // [0,12)
    const int b = rest & 1;
    const int sub = rest >> 1;            // [0,6)
    const int m0 = px * 16;
    const bool isv = sub >= 4;
    const int oc0 = isv ? (32 * h + 16 * (sub - 4)) : (64 * h + 16 * sub);
    const __bf16* W = isv ? Wv : Wq;

    const __bf16* aptr = A + ((size_t)b * NPIX + m0 + l16) * NCH + quad * 8;
    const __bf16* bptr = W + (size_t)(oc0 + l16) * NCH + quad * 8;

    f32x4 acc = {0.f, 0.f, 0.f, 0.f};
#pragma unroll 8
    for (int k = 0; k < NCH; k += 32) {
        bf16x8 af = *(const bf16x8*)(aptr + k);
        bf16x8 bf = *(const bf16x8*)(bptr + k);
        acc = __builtin_amdgcn_mfma_f32_16x16x32_bf16(af, bf, acc, 0, 0, 0);
    }

    const int oc = oc0 + l16;
    const int mb = m0 + quad * 4;

    if (!isv) {
        const float bb = qk_b[oc];
        const int bh = b * NHD + h;
        const int dd = (oc0 & 16) + l16;
        if ((oc0 & 32) == 0) {
            const float qs = 0.17677669529663689f * 1.4426950408889634f;  // hd^-0.5 * log2e
#pragma unroll
            for (int r = 0; r < 4; ++r)
                Qb[((size_t)bh * NPIX + mb + r) * 32 + dd] = (__bf16)((acc[r] + bb) * qs);
        } else {
            __bf16* kp = Kf + ((size_t)(bh * 144 + px) * 64 + (dd >> 3) * 16 + quad * 4) * 8 + (dd & 7);
#pragma unroll
            for (int r = 0; r < 4; ++r) kp[r * 8] = (__bf16)(acc[r] + bb);
        }
    } else {
        const float bb = v_b[oc];
        const int bh = b * NHD + h;
        const int half = (oc0 >> 4) & 1;
        const size_t fb = ((size_t)b * NCH + oc) * NPIX + mb;
        float4 vf_; float* vp = &vf_.x;
        union { __bf16 hh[4]; uint2 u; } pk;
#pragma unroll
        for (int r = 0; r < 4; ++r) {
            float v = acc[r] + bb;
            vp[r] = v; pk.hh[r] = (__bf16)v;
        }
        *(float4*)&v_bu[fb] = vf_;
        *(uint2*)&Vf[((size_t)(bh * 144 + px) * 64 + lane) * 8 + half * 4] = pk.u;
    }
}

// ---------------- MFMA 1x1 conv (proj/fc1/fc2), m-tile-pinned to XCD ---------
// 1D grid 8*OCQ*36 blocks x 4 waves; bid&7 pins m%8; block's 4 waves = 4
// consecutive oc-tiles of the same (b, m-tile) (A-tile reused via L1).
// MODE 2: proj -> +resid(NCHW f32); out_f NCHW f32 (x1) + out_b NHWC bf16 (x1)
// MODE 3: fc1  -> silu; out_b NHWC bf16
// MODE 4: fc2  -> +resid(NCHW f32); out_f NCHW f32 (final)
template <int IC, int OC, int OCQ, int MODE>
__global__ __launch_bounds__(256) void convmm_k(
    const __bf16* __restrict__ A, const __bf16* __restrict__ W,
    const float* __restrict__ bias, const float* __restrict__ resid,
    float* __restrict__ out_f, __bf16* __restrict__ out_b) {
    const int tid = threadIdx.x;
    const int wave = tid >> 6, lane = tid & 63;
    const int l16 = lane & 15, quad = lane >> 4;
    const int xcd = blockIdx.x & 7;
    const int u = blockIdx.x >> 3;        // [0, OCQ*36)
    const int ocq = u % OCQ;
    const int rest = u / OCQ;             // [0,36)
    const int m8 = rest % 18;
    const int b = rest / 18;
    const int m0 = (m8 * 8 + xcd) * 16;
    const int oc0 = (ocq * 4 + wave) * 16;

    const __bf16* aptr = A + ((size_t)b * NPIX + m0 + l16) * IC + quad * 8;
    const __bf16* bptr = W + (size_t)(oc0 + l16) * IC + quad * 8;

    f32x4 acc = {0.f, 0.f, 0.f, 0.f};
#pragma unroll 8
    for (int k = 0; k < IC; k += 32) {
        bf16x8 af = *(const bf16x8*)(aptr + k);
        bf16x8 bf = *(const bf16x8*)(bptr + k);
        acc = __builtin_amdgcn_mfma_f32_16x16x32_bf16(af, bf, acc, 0, 0, 0);
    }

    const int oc = oc0 + l16;
    const int mb = m0 + quad * 4;
    const float bb = bias[oc];

    if constexpr (MODE == 2) {
        const size_t fb = ((size_t)b * OC + oc) * NPIX + mb;
        float4 xr = *(const float4*)&resid[fb];
        const float* xp = &xr.x;
        float4 vf_; float* vp = &vf_.x;
#pragma unroll
        for (int r = 0; r < 4; ++r) {
            float v = acc[r] + bb + xp[r];
            vp[r] = v;
            out_b[((size_t)b * NPIX + mb + r) * OC + oc] = (__bf16)v;
        }
        *(float4*)&out_f[fb] = vf_;
    } else if constexpr (MODE == 3) {
#pragma unroll
        for (int r = 0; r < 4; ++r) {
            float v = acc[r] + bb;
            v = v / (1.f + __expf(-v));
            out_b[((size_t)b * NPIX + mb + r) * OC + oc] = (__bf16)v;
        }
    } else {  // MODE 4
        const size_t fb = ((size_t)b * OC + oc) * NPIX + mb;
        float4 xr = *(const float4*)&resid[fb];
        const float* xp = &xr.x;
        float4 vf_; float* vp = &vf_.x;
#pragma unroll
        for (int r = 0; r < 4; ++r) vp[r] = acc[r] + bb + xp[r];
        *(float4*)&out_f[fb] = vf_;
    }
}

// ---------------- depthwise 7x7, head-pinned (bid&7 = c/32) ------------------
// 1D grid 512: c = (bid&7)*32 + ((bid>>3)&31); b = bid>>8.
__global__ __launch_bounds__(256) void dwconv_k(const float* __restrict__ vb,
                                                const float* __restrict__ pw,
                                                const float* __restrict__ pb,
                                                float* __restrict__ pe) {
    const int tid = threadIdx.x;
    const int r = (int)blockIdx.x >> 3;
    const int c = (blockIdx.x & 7) * 32 + (r & 31);
    const int b = r >> 5;
    __shared__ float plane[NPIX];
    __shared__ float wk[49];
    const size_t base = ((size_t)b * NCH + c) * NPIX;
    for (int i = tid; i < NPIX; i += 256) plane[i] = vb[base + i];
    if (tid < 49) wk[tid] = pw[c * 49 + tid];
    float bb = pb[c];
    __syncthreads();
    for (int p = tid; p < NPIX; p += 256) {
        int y = p / 48, x = p - y * 48;
        float s = bb;
#pragma unroll
        for (int ky = 0; ky < 7; ++ky) {
            int yy = y + ky - 3;
            if ((unsigned)yy < 48u) {
#pragma unroll
                for (int kx = 0; kx < 7; ++kx) {
                    int xx = x + kx - 3;
                    if ((unsigned)xx < 48u) s += wk[ky * 7 + kx] * plane[yy * 48 + xx];
                }
            }
        }
        pe[base + p] = s;
    }
}

// ---------------- MFMA flash attention: in-WG key-split 8, head-pinned -------
// 1D grid 1152 (bid&7 = head -> same XCD as its K/V/Q producer); block = 512
// thr = 8 waves sharing 32 queries; wave w walks tiles [w*18,(w+1)*18).
// Partials reduced via LDS; normalize + pe add -> NHWC bf16.
__global__ __launch_bounds__(512) void attn6_k(const __bf16* __restrict__ Qb,
                                               const __bf16* __restrict__ Kf,
                                               const __bf16* __restrict__ Vf,
                                               const float* __restrict__ pe,
                                               __bf16* __restrict__ opb) {
    const int tid = threadIdx.x;
    const int wave = tid >> 6, lane = tid & 63;
    const int l16 = lane & 15, quad = lane >> 4;
    const int h = blockIdx.x & 7;
    const int r0 = (int)blockIdx.x >> 3;   // [0,144)
    const int qt = r0 % 72;
    const int b = r0 / 72;
    const int qb = qt * 32;
    const int bh = b * NHD + h;

    __shared__ float o_s[8][32][33];   // [wave][d][q], pad 33 -> <=2-way conflicts
    __shared__ float l_s[8][32];       // [wave][q]

    bf16x8 b_q0 = *(const bf16x8*)(Qb + ((size_t)bh * NPIX + qb + l16) * 32 + quad * 8);
    bf16x8 b_q1 = *(const bf16x8*)(Qb + ((size_t)bh * NPIX + qb + 16 + l16) * 32 + quad * 8);

    const __bf16* kf = Kf + ((size_t)(bh * 144 + wave * 18) * 64 + lane) * 8;
    const __bf16* vf = Vf + ((size_t)(bh * 144 + wave * 18) * 64 + lane) * 8;

    f32x4 o00 = {0.f,0.f,0.f,0.f}, o01 = {0.f,0.f,0.f,0.f};
    f32x4 o10 = {0.f,0.f,0.f,0.f}, o11 = {0.f,0.f,0.f,0.f};
    f32x4 l0 = {0.f,0.f,0.f,0.f}, l1 = {0.f,0.f,0.f,0.f};

#pragma unroll 3
    for (int t = 0; t < 18; ++t) {
        bf16x8 a_k = *(const bf16x8*)(kf + (size_t)t * 512);
        bf16x8 va  = *(const bf16x8*)(vf + (size_t)t * 512);
        f32x4 z = {0.f, 0.f, 0.f, 0.f};
        f32x4 s0 = __builtin_amdgcn_mfma_f32_16x16x32_bf16(a_k, b_q0, z, 0, 0, 0);
        f32x4 s1 = __builtin_amdgcn_mfma_f32_16x16x32_bf16(a_k, b_q1, z, 0, 0, 0);
        f32x4 p0, p1;
#pragma unroll
        for (int r = 0; r < 4; ++r) {
            p0[r] = __builtin_amdgcn_exp2f(s0[r]);
            p1[r] = __builtin_amdgcn_exp2f(s1[r]);
        }
        l0 += p0; l1 += p1;
        bf16x8 b0lo = {}, b0hi = {}, b1lo = {}, b1hi = {};
#pragma unroll
        for (int r = 0; r < 4; ++r) {
            __bf16 c0 = (__bf16)p0[r], c1 = (__bf16)p1[r];
            b0lo[r] = c0; b0hi[4 + r] = c0;
            b1lo[r] = c1; b1hi[4 + r] = c1;
        }
        o00 = __builtin_amdgcn_mfma_f32_16x16x32_bf16(va, b0lo, o00, 0, 0, 0);
        o01 = __builtin_amdgcn_mfma_f32_16x16x32_bf16(va, b0hi, o01, 0, 0, 0);
        o10 = __builtin_amdgcn_mfma_f32_16x16x32_bf16(va, b1lo, o10, 0, 0, 0);
        o11 = __builtin_amdgcn_mfma_f32_16x16x32_bf16(va, b1hi, o11, 0, 0, 0);
    }

    float ls0 = l0[0] + l0[1] + l0[2] + l0[3];
    ls0 += __shfl_xor(ls0, 16); ls0 += __shfl_xor(ls0, 32);
    float ls1 = l1[0] + l1[1] + l1[2] + l1[3];
    ls1 += __shfl_xor(ls1, 16); ls1 += __shfl_xor(ls1, 32);

#pragma unroll
    for (int r = 0; r < 4; ++r) {
        o_s[wave][quad * 4 + r][l16]           = o00[r];
        o_s[wave][16 + quad * 4 + r][l16]      = o01[r];
        o_s[wave][quad * 4 + r][16 + l16]      = o10[r];
        o_s[wave][16 + quad * 4 + r][16 + l16] = o11[r];
    }
    if (quad == 0) { l_s[wave][l16] = ls0; l_s[wave][16 + l16] = ls1; }
    __syncthreads();

    // final: 512 thr -> 1024 (q,d)-pairs; q-major for coalesced pe reads
    const int q = tid & 31;            // pixel within tile
    const int d0 = (tid >> 5) * 2;     // channel pair
    float l = 0.f;
#pragma unroll
    for (int w = 0; w < 8; ++w) l += l_s[w][q];
    const float inv = 1.f / l;
    float v0 = 0.f, v1 = 0.f;
#pragma unroll
    for (int w = 0; w < 8; ++w) {
        v0 += o_s[w][d0][q];
        v1 += o_s[w][d0 + 1][q];
    }
    const int n = qb + q;
    const int ch = h * HD + d0;
    v0 = v0 * inv + pe[((size_t)b * NCH + ch) * NPIX + n];
    v1 = v1 * inv + pe[((size_t)b * NCH + ch + 1) * NPIX + n];
    union { __bf16 hh[2]; unsigned u; } pk;
    pk.hh[0] = (__bf16)v0; pk.hh[1] = (__bf16)v1;
    *(unsigned*)&opb[((size_t)b * NPIX + n) * NCH + ch] = pk.u;
}

extern "C" void kernel_launch(void* const* d_in, const int* in_sizes, int n_in,
                              void* d_out, int out_size, void* d_ws, size_t ws_size,
                              hipStream_t stream) {
    const float* x    = (const float*)d_in[0];
    const float* qk_w = (const float*)d_in[1];
    const float* qk_b = (const float*)d_in[2];
    const float* v_w  = (const float*)d_in[3];
    const float* v_b  = (const float*)d_in[4];
    const float* pe_w = (const float*)d_in[5];
    const float* pe_b = (const float*)d_in[6];
    const float* pj_w = (const float*)d_in[7];
    const float* pj_b = (const float*)d_in[8];
    const float* f1_w = (const float*)d_in[9];
    const float* f1_b = (const float*)d_in[10];
    const float* f2_w = (const float*)d_in[11];
    const float* f2_b = (const float*)d_in[12];
    float* out = (float*)d_out;

    const int B = 2;
    const size_t plane = (size_t)NCH * NPIX;       // 589824
    const size_t bp = (size_t)B * plane;           // 1179648

    float* v_bu  = (float*)d_ws;                   // NCHW f32
    float* pe_bu = v_bu + bp;
    float* x1_f  = pe_bu + bp;
    __bf16* Xb   = (__bf16*)(x1_f + bp);           // NHWC bf16 [b][n][256]
    __bf16* opb  = Xb + bp;                        // NHWC bf16 (attn+pe)
    __bf16* x1b  = opb + bp;                       // NHWC bf16
    __bf16* hb   = x1b + bp;                       // NHWC bf16 [b][n][512]
    __bf16* Qb   = hb + 2 * bp;                    // [bh][n][32] (pre-scaled)
    __bf16* Kf   = Qb + bp;                        // QK A-frag tiles
    __bf16* Vf   = Kf + bp;                        // PV A-frag tiles
    __bf16* Wall = Vf + bp;                        // 524288 bf16
    __bf16* Wq = Wall;
    __bf16* Wv = Wall + 131072;
    __bf16* Wp = Wall + 196608;
    __bf16* W1 = Wall + 262144;
    __bf16* W2 = Wall + 393216;

    // 1) x transpose + all weight casts
    prep_k<<<800, 256, 0, stream>>>(x, qk_w, v_w, pj_w, f1_w, f2_w, Xb, Wall);
    // 2) qk conv (-> Qb, Kf) + v conv (-> v_bu f32, Vf), head-pinned
    qkv_k<<<3456, 256, 0, stream>>>(Xb, Wq, Wv, qk_b, v_b, Qb, Kf, v_bu, Vf);
    // 3) pe = dwconv7x7(v_full) + pe_b, head-pinned
    dwconv_k<<<512, 256, 0, stream>>>(v_bu, pe_w, pe_b, pe_bu);
    // 4) attention: in-WG key-split 8, head-pinned; normalize + pe -> opb
    attn6_k<<<1152, 512, 0, stream>>>(Qb, Kf, Vf, pe_bu, opb);
    // 5) x1 = x + proj(o+pe), m-pinned: NCHW f32 + NHWC bf16
    convmm_k<256, 256, 4, 2><<<1152, 256, 0, stream>>>(opb, Wp, pj_b, x, x1_f, x1b);
    // 6) h = silu(fc1(x1)), m-pinned -> NHWC bf16
    convmm_k<256, 512, 8, 3><<<2304, 256, 0, stream>>>(x1b, W1, f1_b, nullptr, nullptr, hb);
    // 7) out = x1 + fc2(h), m-pinned -> NCHW f32
    convmm_k<512, 256, 4, 4><<<1152, 256, 0, stream>>>(hb, W2, f2_b, x1_f, out, nullptr);
}